// Round 1
// baseline (1451.364 us; speedup 1.0000x reference)
//
#include <hip/hip_runtime.h>
#include <hip/hip_bf16.h>
#include <math.h>

#define NB   16
#define NP   1024
#define KN   20
#define LN   10
#define NPT  16384   // NB*NP
#define NCLS 40

// ---------------------------------------------------------------------------
// Kernel 1: kNN within each cloud. One thread per center point.
// Block = 256 threads, 4 blocks per batch (grid 64). Batch pos staged in LDS.
// ---------------------------------------------------------------------------
__global__ __launch_bounds__(256) void knn_k(const float* __restrict__ pos,
                                             int* __restrict__ nbr)
{
    __shared__ float sx[NP], sy[NP], sz[NP], sq[NP];
    const int tid  = threadIdx.x;
    const int blk  = blockIdx.x;          // 0..63
    const int b    = blk >> 2;            // batch
    const int base = b * NP;

    for (int i = tid; i < NP; i += 256) {
        float x = pos[(base + i) * 3 + 0];
        float y = pos[(base + i) * 3 + 1];
        float z = pos[(base + i) * 3 + 2];
        sx[i] = x; sy[i] = y; sz[i] = z;
        sq[i] = x * x + y * y + z * z;    // same op order as ref sum(p*p)
    }
    __syncthreads();

    const int i0 = (blk & 3) * 256 + tid;     // local point index
    const float cx = sx[i0], cy = sy[i0], cz = sz[i0], cq = sq[i0];

    float bd[KN]; int bi[KN];
#pragma unroll
    for (int k = 0; k < KN; ++k) { bd[k] = 3.0e38f; bi[k] = 0; }

    for (int q = 0; q < NP; ++q) {
        if (q == i0) continue;                 // self: ref adds 1e10, never in top-20
        float dot = cx * sx[q] + cy * sy[q] + cz * sz[q];
        float d2  = (cq + sq[q]) - 2.0f * dot; // exact ref formula
        if (d2 < bd[KN - 1]) {                 // strict <: earlier index wins ties
            bd[KN - 1] = d2; bi[KN - 1] = q;
#pragma unroll
            for (int j = KN - 1; j > 0; --j) {
                if (bd[j] < bd[j - 1]) {
                    float td = bd[j]; bd[j] = bd[j - 1]; bd[j - 1] = td;
                    int   ti = bi[j]; bi[j] = bi[j - 1]; bi[j - 1] = ti;
                }
            }
        }
    }

    const int n = base + i0;
#pragma unroll
    for (int k = 0; k < KN; ++k) nbr[n * KN + k] = base + bi[k];
}

// ---------------------------------------------------------------------------
// Jacobi rotation (matches reference math incl. nz / sign(0)=0 semantics).
// All-scalar so everything stays in registers.
// ---------------------------------------------------------------------------
__device__ __forceinline__ void jrot(float& app, float& aqq, float& apq,
                                     float& apr, float& aqr,
                                     float& vp0, float& vp1, float& vp2,
                                     float& vq0, float& vq1, float& vq2)
{
    bool  nz    = fabsf(apq) > 1e-12f;
    float denom = nz ? 2.0f * apq : 1.0f;
    float tau   = (aqq - app) / denom;
    float sg    = (tau > 0.0f) ? 1.0f : ((tau < 0.0f) ? -1.0f : 0.0f);
    float t     = nz ? sg / (fabsf(tau) + sqrtf(1.0f + tau * tau)) : 0.0f;
    float c     = 1.0f / sqrtf(1.0f + t * t);
    float s     = t * c;

    float app_n = c * c * app - 2.0f * c * s * apq + s * s * aqq;
    float aqq_n = s * s * app + 2.0f * c * s * apq + c * c * aqq;
    float apq_n = c * s * (app - aqq) + (c * c - s * s) * apq;
    float apr_n = c * apr - s * aqr;
    float aqr_n = s * apr + c * aqr;
    app = app_n; aqq = aqq_n; apq = apq_n; apr = apr_n; aqr = aqr_n;

    float t0;
    t0 = c * vp0 - s * vq0; vq0 = s * vp0 + c * vq0; vp0 = t0;
    t0 = c * vp1 - s * vq1; vq1 = s * vp1 + c * vq1; vp1 = t0;
    t0 = c * vp2 - s * vq2; vq2 = s * vp2 + c * vq2; vp2 = t0;
}

// ---------------------------------------------------------------------------
// Kernel 2: per-point geometry: clusters, cov(first 10), Jacobi, dir_clusters
// (sign-fixed), h=relu(dir@W1+b1) summed over k, feat=sigmoid(hs@W2+20*b2).
// One thread per point.
// ---------------------------------------------------------------------------
__global__ __launch_bounds__(256) void geom_k(const float* __restrict__ pos,
                                              const int* __restrict__ nbr,
                                              const float* __restrict__ W1,
                                              const float* __restrict__ b1,
                                              const float* __restrict__ W2,
                                              const float* __restrict__ b2,
                                              float* __restrict__ dirc,
                                              float* __restrict__ featO,
                                              float* __restrict__ Vg)
{
    __shared__ float sW1[96], sb1[32], sW2[480], sb2[15];
    const int tid = threadIdx.x;
    for (int i = tid; i < 96;  i += 256) sW1[i] = W1[i];
    if (tid < 32) sb1[tid] = b1[tid];
    for (int i = tid; i < 480; i += 256) sW2[i] = W2[i];
    if (tid < 15) sb2[tid] = b2[tid];
    __syncthreads();

    const int n = blockIdx.x * 256 + tid;
    const float px = pos[n * 3 + 0], py = pos[n * 3 + 1], pz = pos[n * 3 + 2];

    float cl[KN][3];
#pragma unroll
    for (int k = 0; k < KN; ++k) {
        int j = nbr[n * KN + k];
        cl[k][0] = pos[j * 3 + 0] - px;
        cl[k][1] = pos[j * 3 + 1] - py;
        cl[k][2] = pos[j * 3 + 2] - pz;
    }

    float a00 = 0, a01 = 0, a02 = 0, a11 = 0, a12 = 0, a22 = 0;
#pragma unroll
    for (int k = 0; k < LN; ++k) {
        a00 += cl[k][0] * cl[k][0]; a01 += cl[k][0] * cl[k][1]; a02 += cl[k][0] * cl[k][2];
        a11 += cl[k][1] * cl[k][1]; a12 += cl[k][1] * cl[k][2]; a22 += cl[k][2] * cl[k][2];
    }

    float v00 = 1, v01 = 0, v02 = 0,
          v10 = 0, v11 = 1, v12 = 0,
          v20 = 0, v21 = 0, v22 = 1;
#pragma unroll
    for (int it = 0; it < 5; ++it) {
        // (p,q)=(0,1), r=2
        jrot(a00, a11, a01, a02, a12, v00, v10, v20, v01, v11, v21);
        // (p,q)=(0,2), r=1
        jrot(a00, a22, a02, a01, a12, v00, v10, v20, v02, v12, v22);
        // (p,q)=(1,2), r=0
        jrot(a11, a22, a12, a01, a02, v01, v11, v21, v02, v12, v22);
    }

    // dir[k][i] = cl[k] . V[:,i]  (V_ret rows are columns of accumulated V)
    float s2 = 0.0f;
#pragma unroll
    for (int k = 0; k < KN; ++k) {
        float d0 = cl[k][0] * v00 + cl[k][1] * v10 + cl[k][2] * v20;
        float d1 = cl[k][0] * v01 + cl[k][1] * v11 + cl[k][2] * v21;
        float d2 = cl[k][0] * v02 + cl[k][1] * v12 + cl[k][2] * v22;
        cl[k][0] = d0; cl[k][1] = d1; cl[k][2] = d2;
        s2 += d2;
    }
    float sg = (s2 > 0.0f) ? 1.0f : ((s2 < 0.0f) ? -1.0f : 0.0f);

    float hs[32];
#pragma unroll
    for (int c = 0; c < 32; ++c) hs[c] = 0.0f;

#pragma unroll
    for (int k = 0; k < KN; ++k) {
        cl[k][2] *= sg;
        dirc[n * 60 + k * 3 + 0] = cl[k][0];
        dirc[n * 60 + k * 3 + 1] = cl[k][1];
        dirc[n * 60 + k * 3 + 2] = cl[k][2];
#pragma unroll
        for (int c = 0; c < 32; ++c) {
            float h = sb1[c] + cl[k][0] * sW1[c] + cl[k][1] * sW1[32 + c] + cl[k][2] * sW1[64 + c];
            hs[c] += fmaxf(h, 0.0f);
        }
    }

    // V_ret row-major (rows = eigenvectors = columns of accumulated V)
    Vg[n * 9 + 0] = v00; Vg[n * 9 + 1] = v10; Vg[n * 9 + 2] = v20;
    Vg[n * 9 + 3] = v01; Vg[n * 9 + 4] = v11; Vg[n * 9 + 5] = v21;
    Vg[n * 9 + 6] = v02; Vg[n * 9 + 7] = v12; Vg[n * 9 + 8] = v22;

#pragma unroll
    for (int j = 0; j < 15; ++j) {
        float x = 20.0f * sb2[j];
#pragma unroll
        for (int c = 0; c < 32; ++c) x += hs[c] * sW2[c * 15 + j];
        featO[n * 15 + j] = 1.0f / (1.0f + expf(-x));
    }
}

// ---------------------------------------------------------------------------
// Kernel 3: the big per-edge MLP, fused per point.
// One block (256 thr) per point: build concat(20x18) in LDS, H1=relu(.@W3+b3)
// (20x256) in LDS, then out[t] = sum_k relu(H1[k]·W4[:,t] + b4[t]).
// W4 columns read in 32-row chunks into registers (20x reuse via acck[20]).
// ---------------------------------------------------------------------------
__global__ __launch_bounds__(256) void mlp_k(const int* __restrict__ nbr,
                                             const float* __restrict__ dirc,
                                             const float* __restrict__ featI,
                                             const float* __restrict__ Vg,
                                             const float* __restrict__ W3,
                                             const float* __restrict__ b3,
                                             const float* __restrict__ W4,
                                             const float* __restrict__ b4,
                                             float* __restrict__ pf)
{
    __shared__ __align__(16) float H1[20 * 260];   // padded row stride 260 (16B-aligned rows)
    __shared__ float cbuf[360];
    __shared__ int   nbr_s[20];
    __shared__ float Vr_s[9];

    const int t = threadIdx.x;
    const int n = blockIdx.x;

    if (t < 20) nbr_s[t] = nbr[n * KN + t];
    else if (t >= 32 && t < 41) Vr_s[t - 32] = Vg[n * 9 + (t - 32)];
    __syncthreads();

    // Phase A: concat = [dir_clusters(3) | dir_feat(15)] per k
    for (int job = t; job < 360; job += 256) {
        int k = job / 18, c = job - k * 18;
        float val;
        if (c < 3) {
            val = dirc[n * 60 + k * 3 + c];
        } else {
            int e = c - 3, g = e / 3, i = e - g * 3;
            const float* fp = featI + nbr_s[k] * 15 + g * 3;
            val = fp[0] * Vr_s[i * 3 + 0] + fp[1] * Vr_s[i * 3 + 1] + fp[2] * Vr_s[i * 3 + 2];
        }
        cbuf[job] = val;
    }
    __syncthreads();

    // Phase B: H1[k][t] = relu(concat[k]·W3[:,t] + b3[t])
    float w3r[18];
#pragma unroll
    for (int c = 0; c < 18; ++c) w3r[c] = W3[c * 256 + t];
    const float b3t = b3[t];
#pragma unroll
    for (int k = 0; k < 20; ++k) {
        float acc = b3t;
#pragma unroll
        for (int c = 0; c < 18; ++c) acc += cbuf[k * 18 + c] * w3r[c];
        H1[k * 260 + t] = fmaxf(acc, 0.0f);
    }
    __syncthreads();

    // Phase C: acck[k] = H1[k]·W4[:,t]; out = sum_k relu(acck+b4)
    float acck[20];
#pragma unroll
    for (int k = 0; k < 20; ++k) acck[k] = 0.0f;

    for (int c0 = 0; c0 < 256; c0 += 32) {
        float w[32];
#pragma unroll
        for (int j = 0; j < 32; ++j) w[j] = W4[(c0 + j) * 256 + t];
#pragma unroll
        for (int k = 0; k < 20; ++k) {
            const float4* hp = (const float4*)(&H1[k * 260 + c0]);
            float a = acck[k];
#pragma unroll
            for (int j = 0; j < 8; ++j) {
                float4 h = hp[j];
                a = fmaf(h.x, w[4 * j + 0], a);
                a = fmaf(h.y, w[4 * j + 1], a);
                a = fmaf(h.z, w[4 * j + 2], a);
                a = fmaf(h.w, w[4 * j + 3], a);
            }
            acck[k] = a;
        }
    }

    const float b4t = b4[t];
    float pfv = 0.0f;
#pragma unroll
    for (int k = 0; k < 20; ++k) pfv += fmaxf(acck[k] + b4t, 0.0f);
    pf[n * 256 + t] = pfv;
}

// ---------------------------------------------------------------------------
// Kernel 4: per-batch mean over P, elu(ys@Wn1+bn1), log_softmax(y1@Wn2+bn2).
// One block per batch.
// ---------------------------------------------------------------------------
__global__ __launch_bounds__(256) void head_k(const float* __restrict__ pf,
                                              const float* __restrict__ Wn1,
                                              const float* __restrict__ bn1,
                                              const float* __restrict__ Wn2,
                                              const float* __restrict__ bn2,
                                              float* __restrict__ out)
{
    __shared__ float ysh[256], y1h[256], zsh[64];
    const int t = threadIdx.x, b = blockIdx.x;

    float s = 0.0f;
    const float* base = pf + (size_t)b * NP * 256;
    for (int p = 0; p < NP; ++p) s += base[p * 256 + t];
    ysh[t] = s * (1.0f / 1024.0f);
    __syncthreads();

    float acc = bn1[t];
    for (int c = 0; c < 256; ++c) acc += ysh[c] * Wn1[c * 256 + t];
    y1h[t] = (acc > 0.0f) ? acc : expm1f(acc);
    __syncthreads();

    if (t < NCLS) {
        float z = bn2[t];
        for (int c = 0; c < 256; ++c) z += y1h[c] * Wn2[c * NCLS + t];
        zsh[t] = z;
    }
    __syncthreads();

    if (t < 64) {
        float v = (t < NCLS) ? zsh[t] : -3.0e38f;
        float m = v;
#pragma unroll
        for (int off = 32; off >= 1; off >>= 1) m = fmaxf(m, __shfl_xor(m, off));
        float e = (t < NCLS) ? expf(zsh[t] - m) : 0.0f;
#pragma unroll
        for (int off = 32; off >= 1; off >>= 1) e += __shfl_xor(e, off);
        if (t < NCLS) out[b * NCLS + t] = zsh[t] - m - logf(e);
    }
}

// ---------------------------------------------------------------------------
extern "C" void kernel_launch(void* const* d_in, const int* in_sizes, int n_in,
                              void* d_out, int out_size, void* d_ws, size_t ws_size,
                              hipStream_t stream)
{
    const float* pos = (const float*)d_in[0];
    const float* W1  = (const float*)d_in[1];
    const float* b1  = (const float*)d_in[2];
    const float* W2  = (const float*)d_in[3];
    const float* b2  = (const float*)d_in[4];
    const float* W3  = (const float*)d_in[5];
    const float* b3  = (const float*)d_in[6];
    const float* W4  = (const float*)d_in[7];
    const float* b4  = (const float*)d_in[8];
    const float* Wn1 = (const float*)d_in[9];
    const float* bn1 = (const float*)d_in[10];
    const float* Wn2 = (const float*)d_in[11];
    const float* bn2 = (const float*)d_in[12];
    float* out = (float*)d_out;

    char* ws = (char*)d_ws;
    // workspace layout (bytes), all 256B aligned
    int*   nbr  = (int*)(ws + 0);                  //  1,310,720
    float* dirc = (float*)(ws + 1310720);          //  3,932,160
    float* feat = (float*)(ws + 5242880);          //    983,040
    float* Vg   = (float*)(ws + 6225920);          //    589,824
    float* pf   = (float*)(ws + 6815744);          // 16,777,216  (total ~23.6 MB)

    knn_k <<<64,    256, 0, stream>>>(pos, nbr);
    geom_k<<<64,    256, 0, stream>>>(pos, nbr, W1, b1, W2, b2, dirc, feat, Vg);
    mlp_k <<<NPT,   256, 0, stream>>>(nbr, dirc, feat, Vg, W3, b3, W4, b4, pf);
    head_k<<<NB,    256, 0, stream>>>(pf, Wn1, bn1, Wn2, bn2, out);
}

// Round 3
// 627.219 us; speedup vs baseline: 2.3140x; 2.3140x over previous
//
#include <hip/hip_runtime.h>
#include <hip/hip_bf16.h>
#include <math.h>

#define NB   16
#define NP   1024
#define KN   20
#define LN   10
#define NPT  16384   // NB*NP
#define NCLS 40

typedef short bf16x8 __attribute__((ext_vector_type(8)));
typedef float f32x4  __attribute__((ext_vector_type(4)));

__device__ __forceinline__ short f2bf(float x) {
    __hip_bfloat16 h = __float2bfloat16(x);
    return *reinterpret_cast<short*>(&h);
}

// ---------------------------------------------------------------------------
// Kernel 0: weight prep — W3 (18x256) -> W3T bf16 [256][32] (k zero-padded),
//           W4 (256x256) -> W4T bf16 [256][256]  (both [n][k] layout).
// ---------------------------------------------------------------------------
__global__ __launch_bounds__(256) void prep_k(const float* __restrict__ W3,
                                              const float* __restrict__ W4,
                                              short* __restrict__ W3T,
                                              short* __restrict__ W4T)
{
    const int k = blockIdx.x;    // 0..255
    const int n = threadIdx.x;   // 0..255
    W4T[n * 256 + k] = f2bf(W4[k * 256 + n]);
    if (k < 32) {
        float v = (k < 18) ? W3[k * 256 + n] : 0.0f;
        W3T[n * 32 + k] = f2bf(v);
    }
}

// ---------------------------------------------------------------------------
// Kernel 1: kNN within each cloud. One thread per center point.
// ---------------------------------------------------------------------------
__global__ __launch_bounds__(256) void knn_k(const float* __restrict__ pos,
                                             int* __restrict__ nbr)
{
    __shared__ float sx[NP], sy[NP], sz[NP], sq[NP];
    const int tid  = threadIdx.x;
    const int blk  = blockIdx.x;          // 0..63
    const int b    = blk >> 2;            // batch
    const int base = b * NP;

    for (int i = tid; i < NP; i += 256) {
        float x = pos[(base + i) * 3 + 0];
        float y = pos[(base + i) * 3 + 1];
        float z = pos[(base + i) * 3 + 2];
        sx[i] = x; sy[i] = y; sz[i] = z;
        sq[i] = x * x + y * y + z * z;
    }
    __syncthreads();

    const int i0 = (blk & 3) * 256 + tid;
    const float cx = sx[i0], cy = sy[i0], cz = sz[i0], cq = sq[i0];

    float bd[KN]; int bi[KN];
#pragma unroll
    for (int k = 0; k < KN; ++k) { bd[k] = 3.0e38f; bi[k] = 0; }

    for (int q = 0; q < NP; ++q) {
        if (q == i0) continue;
        float dot = cx * sx[q] + cy * sy[q] + cz * sz[q];
        float d2  = (cq + sq[q]) - 2.0f * dot;
        if (d2 < bd[KN - 1]) {
            bd[KN - 1] = d2; bi[KN - 1] = q;
#pragma unroll
            for (int j = KN - 1; j > 0; --j) {
                if (bd[j] < bd[j - 1]) {
                    float td = bd[j]; bd[j] = bd[j - 1]; bd[j - 1] = td;
                    int   ti = bi[j]; bi[j] = bi[j - 1]; bi[j - 1] = ti;
                }
            }
        }
    }

    const int n = base + i0;
#pragma unroll
    for (int k = 0; k < KN; ++k) nbr[n * KN + k] = base + bi[k];
}

// ---------------------------------------------------------------------------
// Jacobi rotation (matches reference math incl. nz / sign(0)=0 semantics).
// ---------------------------------------------------------------------------
__device__ __forceinline__ void jrot(float& app, float& aqq, float& apq,
                                     float& apr, float& aqr,
                                     float& vp0, float& vp1, float& vp2,
                                     float& vq0, float& vq1, float& vq2)
{
    bool  nz    = fabsf(apq) > 1e-12f;
    float denom = nz ? 2.0f * apq : 1.0f;
    float tau   = (aqq - app) / denom;
    float sg    = (tau > 0.0f) ? 1.0f : ((tau < 0.0f) ? -1.0f : 0.0f);
    float t     = nz ? sg / (fabsf(tau) + sqrtf(1.0f + tau * tau)) : 0.0f;
    float c     = 1.0f / sqrtf(1.0f + t * t);
    float s     = t * c;

    float app_n = c * c * app - 2.0f * c * s * apq + s * s * aqq;
    float aqq_n = s * s * app + 2.0f * c * s * apq + c * c * aqq;
    float apq_n = c * s * (app - aqq) + (c * c - s * s) * apq;
    float apr_n = c * apr - s * aqr;
    float aqr_n = s * apr + c * aqr;
    app = app_n; aqq = aqq_n; apq = apq_n; apr = apr_n; aqr = aqr_n;

    float t0;
    t0 = c * vp0 - s * vq0; vq0 = s * vp0 + c * vq0; vp0 = t0;
    t0 = c * vp1 - s * vq1; vq1 = s * vp1 + c * vq1; vp1 = t0;
    t0 = c * vp2 - s * vq2; vq2 = s * vp2 + c * vq2; vp2 = t0;
}

// ---------------------------------------------------------------------------
// Kernel 2: per-point geometry (unchanged, known-correct).
// ---------------------------------------------------------------------------
__global__ __launch_bounds__(256) void geom_k(const float* __restrict__ pos,
                                              const int* __restrict__ nbr,
                                              const float* __restrict__ W1,
                                              const float* __restrict__ b1,
                                              const float* __restrict__ W2,
                                              const float* __restrict__ b2,
                                              float* __restrict__ dirc,
                                              float* __restrict__ featO,
                                              float* __restrict__ Vg)
{
    __shared__ float sW1[96], sb1[32], sW2[480], sb2[15];
    const int tid = threadIdx.x;
    for (int i = tid; i < 96;  i += 256) sW1[i] = W1[i];
    if (tid < 32) sb1[tid] = b1[tid];
    for (int i = tid; i < 480; i += 256) sW2[i] = W2[i];
    if (tid < 15) sb2[tid] = b2[tid];
    __syncthreads();

    const int n = blockIdx.x * 256 + tid;
    const float px = pos[n * 3 + 0], py = pos[n * 3 + 1], pz = pos[n * 3 + 2];

    float cl[KN][3];
#pragma unroll
    for (int k = 0; k < KN; ++k) {
        int j = nbr[n * KN + k];
        cl[k][0] = pos[j * 3 + 0] - px;
        cl[k][1] = pos[j * 3 + 1] - py;
        cl[k][2] = pos[j * 3 + 2] - pz;
    }

    float a00 = 0, a01 = 0, a02 = 0, a11 = 0, a12 = 0, a22 = 0;
#pragma unroll
    for (int k = 0; k < LN; ++k) {
        a00 += cl[k][0] * cl[k][0]; a01 += cl[k][0] * cl[k][1]; a02 += cl[k][0] * cl[k][2];
        a11 += cl[k][1] * cl[k][1]; a12 += cl[k][1] * cl[k][2]; a22 += cl[k][2] * cl[k][2];
    }

    float v00 = 1, v01 = 0, v02 = 0,
          v10 = 0, v11 = 1, v12 = 0,
          v20 = 0, v21 = 0, v22 = 1;
#pragma unroll
    for (int it = 0; it < 5; ++it) {
        jrot(a00, a11, a01, a02, a12, v00, v10, v20, v01, v11, v21);
        jrot(a00, a22, a02, a01, a12, v00, v10, v20, v02, v12, v22);
        jrot(a11, a22, a12, a01, a02, v01, v11, v21, v02, v12, v22);
    }

    float s2 = 0.0f;
#pragma unroll
    for (int k = 0; k < KN; ++k) {
        float d0 = cl[k][0] * v00 + cl[k][1] * v10 + cl[k][2] * v20;
        float d1 = cl[k][0] * v01 + cl[k][1] * v11 + cl[k][2] * v21;
        float d2 = cl[k][0] * v02 + cl[k][1] * v12 + cl[k][2] * v22;
        cl[k][0] = d0; cl[k][1] = d1; cl[k][2] = d2;
        s2 += d2;
    }
    float sg = (s2 > 0.0f) ? 1.0f : ((s2 < 0.0f) ? -1.0f : 0.0f);

    float hs[32];
#pragma unroll
    for (int c = 0; c < 32; ++c) hs[c] = 0.0f;

#pragma unroll
    for (int k = 0; k < KN; ++k) {
        cl[k][2] *= sg;
        dirc[n * 60 + k * 3 + 0] = cl[k][0];
        dirc[n * 60 + k * 3 + 1] = cl[k][1];
        dirc[n * 60 + k * 3 + 2] = cl[k][2];
#pragma unroll
        for (int c = 0; c < 32; ++c) {
            float h = sb1[c] + cl[k][0] * sW1[c] + cl[k][1] * sW1[32 + c] + cl[k][2] * sW1[64 + c];
            hs[c] += fmaxf(h, 0.0f);
        }
    }

    Vg[n * 9 + 0] = v00; Vg[n * 9 + 1] = v10; Vg[n * 9 + 2] = v20;
    Vg[n * 9 + 3] = v01; Vg[n * 9 + 4] = v11; Vg[n * 9 + 5] = v21;
    Vg[n * 9 + 6] = v02; Vg[n * 9 + 7] = v12; Vg[n * 9 + 8] = v22;

#pragma unroll
    for (int j = 0; j < 15; ++j) {
        float x = 20.0f * sb2[j];
#pragma unroll
        for (int c = 0; c < 32; ++c) x += hs[c] * sW2[c * 15 + j];
        featO[n * 15 + j] = 1.0f / (1.0f + expf(-x));
    }
}

// ---------------------------------------------------------------------------
// Kernel 3: per-edge MLP via MFMA. One block (4 waves) per 2 points.
// Rows: point p -> rows [32p, 32p+20) valid, rest zero-pad (M=64).
// Phase A: concat (bf16) in LDS [64][40] (cols 18..31 zero).
// Phase B: H1 = relu(concat@W3 + b3) via mfma, bf16 -> LDS [64][264].
// Phase C: h2 = H1@W4 via mfma over 8 K-chunks, W4T read from global (L2).
// Epilogue: relu(+b4), mask pad rows, per-point sum via shfl_xor.
// ---------------------------------------------------------------------------
__global__ __launch_bounds__(256) void mlp_k(const int* __restrict__ nbr,
                                             const float* __restrict__ dirc,
                                             const float* __restrict__ featI,
                                             const float* __restrict__ Vg,
                                             const short* __restrict__ W3T,
                                             const float* __restrict__ b3,
                                             const short* __restrict__ W4T,
                                             const float* __restrict__ b4,
                                             float* __restrict__ pf)
{
    __shared__ __align__(16) short H1L[64 * 264];    // 33,792 B, stride 264 (2-way free)
    __shared__ __align__(16) short concatL[64 * 40]; //  5,120 B, stride 40  (2-way free)
    __shared__ int   nbr_s[40];
    __shared__ float Vr_s[18];

    const int t   = threadIdx.x;
    const int l   = t & 63;
    const int lg  = l >> 4;            // lane group 0..3
    const int lc  = l & 15;            // lane col 0..15
    const int n0w = (t >> 6) * 64;     // wave's N-column base
    const int blk = blockIdx.x;        // 0..8191, owns points 2*blk, 2*blk+1

    if (t < 40) nbr_s[t] = nbr[blk * 40 + t];
    if (t >= 64 && t < 82) Vr_s[t - 64] = Vg[blk * 18 + (t - 64)];
    // zero concat (1280 ints)
    for (int i = t; i < 1280; i += 256) ((int*)concatL)[i] = 0;
    __syncthreads();

    // Phase A: fill concat rows (2 points x 20 edges x 18 cols)
    for (int job = t; job < 720; job += 256) {
        int p  = job / 360;
        int rr = job - p * 360;
        int k  = rr / 18;
        int c  = rr - k * 18;
        int ptg = blk * 2 + p;
        float val;
        if (c < 3) {
            val = dirc[ptg * 60 + k * 3 + c];
        } else {
            int e = c - 3, g = e / 3, i = e - g * 3;
            const float* fp = featI + nbr_s[p * 20 + k] * 15 + g * 3;
            const float* Vr = Vr_s + p * 9;
            val = fp[0] * Vr[i * 3 + 0] + fp[1] * Vr[i * 3 + 1] + fp[2] * Vr[i * 3 + 2];
        }
        concatL[(32 * p + k) * 40 + c] = f2bf(val);
    }
    __syncthreads();

    // Phase B: H1 = relu(concat @ W3 + b3), one K-chunk (K=32)
    {
        f32x4 accB[4][4];
#pragma unroll
        for (int mt = 0; mt < 4; ++mt)
#pragma unroll
            for (int nt = 0; nt < 4; ++nt)
#pragma unroll
                for (int r = 0; r < 4; ++r) accB[mt][nt][r] = 0.0f;

        bf16x8 aB[4], bB[4];
#pragma unroll
        for (int mt = 0; mt < 4; ++mt)
            aB[mt] = *(const bf16x8*)&concatL[(mt * 16 + lc) * 40 + lg * 8];
#pragma unroll
        for (int nt = 0; nt < 4; ++nt)
            bB[nt] = *(const bf16x8*)&W3T[(n0w + nt * 16 + lc) * 32 + lg * 8];
#pragma unroll
        for (int mt = 0; mt < 4; ++mt)
#pragma unroll
            for (int nt = 0; nt < 4; ++nt)
                accB[mt][nt] = __builtin_amdgcn_mfma_f32_16x16x32_bf16(aB[mt], bB[nt], accB[mt][nt], 0, 0, 0);

#pragma unroll
        for (int nt = 0; nt < 4; ++nt) {
            int col = n0w + nt * 16 + lc;
            float b3v = b3[col];
#pragma unroll
            for (int mt = 0; mt < 4; ++mt)
#pragma unroll
                for (int r = 0; r < 4; ++r) {
                    int row = mt * 16 + lg * 4 + r;
                    float v = fmaxf(accB[mt][nt][r] + b3v, 0.0f);
                    H1L[row * 264 + col] = f2bf(v);
                }
        }
    }
    __syncthreads();

    // Phase C: h2 = H1 @ W4 over 8 K-chunks of 32
    f32x4 acc[4][4];
#pragma unroll
    for (int mt = 0; mt < 4; ++mt)
#pragma unroll
        for (int nt = 0; nt < 4; ++nt)
#pragma unroll
            for (int r = 0; r < 4; ++r) acc[mt][nt][r] = 0.0f;

#pragma unroll
    for (int ch = 0; ch < 8; ++ch) {
        bf16x8 a[4], b[4];
#pragma unroll
        for (int mt = 0; mt < 4; ++mt)
            a[mt] = *(const bf16x8*)&H1L[(mt * 16 + lc) * 264 + ch * 32 + lg * 8];
#pragma unroll
        for (int nt = 0; nt < 4; ++nt)
            b[nt] = *(const bf16x8*)&W4T[(n0w + nt * 16 + lc) * 256 + ch * 32 + lg * 8];
#pragma unroll
        for (int mt = 0; mt < 4; ++mt)
#pragma unroll
            for (int nt = 0; nt < 4; ++nt)
                acc[mt][nt] = __builtin_amdgcn_mfma_f32_16x16x32_bf16(a[mt], b[nt], acc[mt][nt], 0, 0, 0);
    }

    // Epilogue: relu(+b4), mask pad rows, per-point sums
    const float mask = (lg == 0) ? 1.0f : 0.0f;   // odd m-tiles: rows 16..19 only
#pragma unroll
    for (int nt = 0; nt < 4; ++nt) {
        int col = n0w + nt * 16 + lc;
        float b4v = b4[col];
        float s0 = 0.0f, s1 = 0.0f;
#pragma unroll
        for (int r = 0; r < 4; ++r) {
            s0 += fmaxf(acc[0][nt][r] + b4v, 0.0f);
            s0 += fmaxf(acc[1][nt][r] + b4v, 0.0f) * mask;
            s1 += fmaxf(acc[2][nt][r] + b4v, 0.0f);
            s1 += fmaxf(acc[3][nt][r] + b4v, 0.0f) * mask;
        }
        s0 += __shfl_xor(s0, 16); s0 += __shfl_xor(s0, 32);
        s1 += __shfl_xor(s1, 16); s1 += __shfl_xor(s1, 32);
        if (l < 16) {
            pf[(blk * 2 + 0) * 256 + col] = s0;
            pf[(blk * 2 + 1) * 256 + col] = s1;
        }
    }
}

// ---------------------------------------------------------------------------
// Kernel 4: head (unchanged).
// ---------------------------------------------------------------------------
__global__ __launch_bounds__(256) void head_k(const float* __restrict__ pf,
                                              const float* __restrict__ Wn1,
                                              const float* __restrict__ bn1,
                                              const float* __restrict__ Wn2,
                                              const float* __restrict__ bn2,
                                              float* __restrict__ out)
{
    __shared__ float ysh[256], y1h[256], zsh[64];
    const int t = threadIdx.x, b = blockIdx.x;

    float s = 0.0f;
    const float* base = pf + (size_t)b * NP * 256;
    for (int p = 0; p < NP; ++p) s += base[p * 256 + t];
    ysh[t] = s * (1.0f / 1024.0f);
    __syncthreads();

    float acc = bn1[t];
    for (int c = 0; c < 256; ++c) acc += ysh[c] * Wn1[c * 256 + t];
    y1h[t] = (acc > 0.0f) ? acc : expm1f(acc);
    __syncthreads();

    if (t < NCLS) {
        float z = bn2[t];
        for (int c = 0; c < 256; ++c) z += y1h[c] * Wn2[c * NCLS + t];
        zsh[t] = z;
    }
    __syncthreads();

    if (t < 64) {
        float v = (t < NCLS) ? zsh[t] : -3.0e38f;
        float m = v;
#pragma unroll
        for (int off = 32; off >= 1; off >>= 1) m = fmaxf(m, __shfl_xor(m, off));
        float e = (t < NCLS) ? expf(zsh[t] - m) : 0.0f;
#pragma unroll
        for (int off = 32; off >= 1; off >>= 1) e += __shfl_xor(e, off);
        if (t < NCLS) out[b * NCLS + t] = zsh[t] - m - logf(e);
    }
}

// ---------------------------------------------------------------------------
extern "C" void kernel_launch(void* const* d_in, const int* in_sizes, int n_in,
                              void* d_out, int out_size, void* d_ws, size_t ws_size,
                              hipStream_t stream)
{
    const float* pos = (const float*)d_in[0];
    const float* W1  = (const float*)d_in[1];
    const float* b1  = (const float*)d_in[2];
    const float* W2  = (const float*)d_in[3];
    const float* b2  = (const float*)d_in[4];
    const float* W3  = (const float*)d_in[5];
    const float* b3  = (const float*)d_in[6];
    const float* W4  = (const float*)d_in[7];
    const float* b4  = (const float*)d_in[8];
    const float* Wn1 = (const float*)d_in[9];
    const float* bn1 = (const float*)d_in[10];
    const float* Wn2 = (const float*)d_in[11];
    const float* bn2 = (const float*)d_in[12];
    float* out = (float*)d_out;

    char* ws = (char*)d_ws;
    // workspace layout (bytes)
    int*   nbr  = (int*)(ws + 0);                  //  1,310,720
    float* dirc = (float*)(ws + 1310720);          //  3,932,160
    float* feat = (float*)(ws + 5242880);          //    983,040
    float* Vg   = (float*)(ws + 6225920);          //    589,824
    float* pf   = (float*)(ws + 6815744);          // 16,777,216
    short* W4T  = (short*)(ws + 23592960);         //    131,072
    short* W3T  = (short*)(ws + 23724032);         //     16,384  (end ~23.74 MB)

    prep_k<<<256,  256, 0, stream>>>(W3, W4, W3T, W4T);
    knn_k <<<64,   256, 0, stream>>>(pos, nbr);
    geom_k<<<64,   256, 0, stream>>>(pos, nbr, W1, b1, W2, b2, dirc, feat, Vg);
    mlp_k <<<NPT/2,256, 0, stream>>>(nbr, dirc, feat, Vg, W3T, b3, W4T, b4, pf);
    head_k<<<NB,   256, 0, stream>>>(pf, Wn1, bn1, Wn2, bn2, out);
}

// Round 4
// 475.861 us; speedup vs baseline: 3.0500x; 1.3181x over previous
//
#include <hip/hip_runtime.h>
#include <hip/hip_bf16.h>
#include <math.h>

#define NB   16
#define NP   1024
#define KN   20
#define LN   10
#define NPT  16384   // NB*NP
#define NCLS 40

typedef short bf16x8 __attribute__((ext_vector_type(8)));
typedef float f32x4  __attribute__((ext_vector_type(4)));
typedef unsigned long long u64;

__device__ __forceinline__ short f2bf(float x) {
    __hip_bfloat16 h = __float2bfloat16(x);
    return *reinterpret_cast<short*>(&h);
}

// ---------------------------------------------------------------------------
// Kernel 0: weight prep — W3 (18x256) -> W3T bf16 [256][32] (k zero-padded),
//           W4 (256x256) -> W4T bf16 [256][256]  (both [n][k] layout).
// ---------------------------------------------------------------------------
__global__ __launch_bounds__(256) void prep_k(const float* __restrict__ W3,
                                              const float* __restrict__ W4,
                                              short* __restrict__ W3T,
                                              short* __restrict__ W4T)
{
    const int k = blockIdx.x;    // 0..255
    const int n = threadIdx.x;   // 0..255
    W4T[n * 256 + k] = f2bf(W4[k * 256 + n]);
    if (k < 32) {
        float v = (k < 18) ? W3[k * 256 + n] : 0.0f;
        W3T[n * 32 + k] = f2bf(v);
    }
}

// ---------------------------------------------------------------------------
// Kernel 1: kNN. 8 scanner-lanes per center, 32 centers per block (256 thr).
// Grid = 512 blocks (32 per batch). Keys are u64 (monotone d2 bits << 32)|idx
// so ordering is exact (d2 asc, idx asc on ties) and scan-order independent.
// Merge via 3-level shfl_xor bitonic tree (static indices only).
// ---------------------------------------------------------------------------
__global__ __launch_bounds__(256) void knn_k(const float* __restrict__ pos,
                                             int* __restrict__ nbr)
{
    __shared__ float4 sp[NP];            // 16 KB
    const int t    = threadIdx.x;
    const int blk  = blockIdx.x;         // 0..511
    const int b    = blk >> 5;           // 32 blocks per batch
    const int base = b * NP;

    for (int i = t; i < NP; i += 256) {
        float x = pos[(base + i) * 3 + 0];
        float y = pos[(base + i) * 3 + 1];
        float z = pos[(base + i) * 3 + 2];
        sp[i] = make_float4(x, y, z, x * x + y * y + z * z);
    }
    __syncthreads();

    const int s    = t & 7;                        // scanner lane 0..7
    const int cLoc = (blk & 31) * 32 + (t >> 3);   // local center 0..1023
    const float4 cp = sp[cLoc];

    u64 A[20];
#pragma unroll
    for (int k = 0; k < 20; ++k) A[k] = ~0ull;

    const int q0 = s * 128;
    for (int ii = 0; ii < 128; ++ii) {
        int i = (ii + s) & 127;          // bank-staggered scan order
        int q = q0 + i;
        float4 p = sp[q];
        float dot = cp.x * p.x + cp.y * p.y + cp.z * p.z;
        float d2  = (cp.w + p.w) - 2.0f * dot;
        unsigned u = __float_as_uint(d2);
        u ^= (unsigned)(((int)u >> 31) | 0x80000000);   // monotone map
        u64 key = ((u64)u << 32) | (unsigned)q;
        if (q == cLoc) key = ~0ull;                     // self-exclusion
        if (key < A[19]) {
            A[19] = key;
#pragma unroll
            for (int j = 19; j > 0; --j)
                if (A[j] < A[j - 1]) { u64 tmp = A[j]; A[j] = A[j - 1]; A[j - 1] = tmp; }
        }
    }

    // 3-level merge tree across scanner lanes (1,2,4). After each level both
    // halves hold the identical merged sorted 20-list (merge is symmetric).
#pragma unroll
    for (int m = 1; m <= 4; m <<= 1) {
        u64 Bv[20];
#pragma unroll
        for (int k = 0; k < 20; ++k) Bv[k] = __shfl_xor(A[k], m);
        u64 L[32];
#pragma unroll
        for (int i = 0; i < 12; ++i) L[i] = A[i];               // min(A[i], MAX)
#pragma unroll
        for (int i = 12; i < 20; ++i) L[i] = (A[i] < Bv[31 - i]) ? A[i] : Bv[31 - i];
#pragma unroll
        for (int i = 20; i < 32; ++i) L[i] = Bv[31 - i];        // min(MAX, B)
        // L is bitonic and contains the 32 smallest of the union; sort it.
#pragma unroll
        for (int d = 16; d >= 1; d >>= 1)
#pragma unroll
            for (int i = 0; i < 32; ++i)
                if ((i & d) == 0) {
                    u64 lo = (L[i] < L[i + d]) ? L[i] : L[i + d];
                    u64 hi = (L[i] < L[i + d]) ? L[i + d] : L[i];
                    L[i] = lo; L[i + d] = hi;
                }
#pragma unroll
        for (int k = 0; k < 20; ++k) A[k] = L[k];
    }

    if (s == 0) {
        const int n = base + cLoc;
#pragma unroll
        for (int k = 0; k < 20; ++k)
            nbr[n * KN + k] = base + (int)(unsigned)(A[k] & 0xFFFFFFFFull);
    }
}

// ---------------------------------------------------------------------------
// Jacobi rotation (matches reference math incl. nz / sign(0)=0 semantics).
// ---------------------------------------------------------------------------
__device__ __forceinline__ void jrot(float& app, float& aqq, float& apq,
                                     float& apr, float& aqr,
                                     float& vp0, float& vp1, float& vp2,
                                     float& vq0, float& vq1, float& vq2)
{
    bool  nz    = fabsf(apq) > 1e-12f;
    float denom = nz ? 2.0f * apq : 1.0f;
    float tau   = (aqq - app) / denom;
    float sg    = (tau > 0.0f) ? 1.0f : ((tau < 0.0f) ? -1.0f : 0.0f);
    float t     = nz ? sg / (fabsf(tau) + sqrtf(1.0f + tau * tau)) : 0.0f;
    float c     = 1.0f / sqrtf(1.0f + t * t);
    float s     = t * c;

    float app_n = c * c * app - 2.0f * c * s * apq + s * s * aqq;
    float aqq_n = s * s * app + 2.0f * c * s * apq + c * c * aqq;
    float apq_n = c * s * (app - aqq) + (c * c - s * s) * apq;
    float apr_n = c * apr - s * aqr;
    float aqr_n = s * apr + c * aqr;
    app = app_n; aqq = aqq_n; apq = apq_n; apr = apr_n; aqr = aqr_n;

    float t0;
    t0 = c * vp0 - s * vq0; vq0 = s * vp0 + c * vq0; vp0 = t0;
    t0 = c * vp1 - s * vq1; vq1 = s * vp1 + c * vq1; vp1 = t0;
    t0 = c * vp2 - s * vq2; vq2 = s * vp2 + c * vq2; vp2 = t0;
}

// ---------------------------------------------------------------------------
// Kernel 2: per-point geometry. Block=64, grid=256 (all CUs covered).
// ---------------------------------------------------------------------------
__global__ __launch_bounds__(64) void geom_k(const float* __restrict__ pos,
                                             const int* __restrict__ nbr,
                                             const float* __restrict__ W1,
                                             const float* __restrict__ b1,
                                             const float* __restrict__ W2,
                                             const float* __restrict__ b2,
                                             float* __restrict__ dirc,
                                             float* __restrict__ featO,
                                             float* __restrict__ Vg)
{
    __shared__ float sW1[96], sb1[32], sb2[15], sW2[480];
    const int tid = threadIdx.x;
    for (int i = tid; i < 96;  i += 64) sW1[i] = W1[i];
    if (tid < 32) sb1[tid] = b1[tid];
    for (int i = tid; i < 480; i += 64) sW2[i] = W2[i];
    if (tid < 15) sb2[tid] = b2[tid];
    __syncthreads();

    const int n = blockIdx.x * 64 + tid;
    const float px = pos[n * 3 + 0], py = pos[n * 3 + 1], pz = pos[n * 3 + 2];

    float cl[KN][3];
#pragma unroll
    for (int k = 0; k < KN; ++k) {
        int j = nbr[n * KN + k];
        cl[k][0] = pos[j * 3 + 0] - px;
        cl[k][1] = pos[j * 3 + 1] - py;
        cl[k][2] = pos[j * 3 + 2] - pz;
    }

    float a00 = 0, a01 = 0, a02 = 0, a11 = 0, a12 = 0, a22 = 0;
#pragma unroll
    for (int k = 0; k < LN; ++k) {
        a00 += cl[k][0] * cl[k][0]; a01 += cl[k][0] * cl[k][1]; a02 += cl[k][0] * cl[k][2];
        a11 += cl[k][1] * cl[k][1]; a12 += cl[k][1] * cl[k][2]; a22 += cl[k][2] * cl[k][2];
    }

    float v00 = 1, v01 = 0, v02 = 0,
          v10 = 0, v11 = 1, v12 = 0,
          v20 = 0, v21 = 0, v22 = 1;
#pragma unroll
    for (int it = 0; it < 5; ++it) {
        jrot(a00, a11, a01, a02, a12, v00, v10, v20, v01, v11, v21);
        jrot(a00, a22, a02, a01, a12, v00, v10, v20, v02, v12, v22);
        jrot(a11, a22, a12, a01, a02, v01, v11, v21, v02, v12, v22);
    }

    float s2 = 0.0f;
#pragma unroll
    for (int k = 0; k < KN; ++k) {
        float d0 = cl[k][0] * v00 + cl[k][1] * v10 + cl[k][2] * v20;
        float d1 = cl[k][0] * v01 + cl[k][1] * v11 + cl[k][2] * v21;
        float d2 = cl[k][0] * v02 + cl[k][1] * v12 + cl[k][2] * v22;
        cl[k][0] = d0; cl[k][1] = d1; cl[k][2] = d2;
        s2 += d2;
    }
    float sg = (s2 > 0.0f) ? 1.0f : ((s2 < 0.0f) ? -1.0f : 0.0f);

    float hs[32];
#pragma unroll
    for (int c = 0; c < 32; ++c) hs[c] = 0.0f;

#pragma unroll
    for (int k = 0; k < KN; ++k) {
        cl[k][2] *= sg;
        dirc[n * 60 + k * 3 + 0] = cl[k][0];
        dirc[n * 60 + k * 3 + 1] = cl[k][1];
        dirc[n * 60 + k * 3 + 2] = cl[k][2];
#pragma unroll
        for (int c = 0; c < 32; ++c) {
            float h = sb1[c] + cl[k][0] * sW1[c] + cl[k][1] * sW1[32 + c] + cl[k][2] * sW1[64 + c];
            hs[c] += fmaxf(h, 0.0f);
        }
    }

    Vg[n * 9 + 0] = v00; Vg[n * 9 + 1] = v10; Vg[n * 9 + 2] = v20;
    Vg[n * 9 + 3] = v01; Vg[n * 9 + 4] = v11; Vg[n * 9 + 5] = v21;
    Vg[n * 9 + 6] = v02; Vg[n * 9 + 7] = v12; Vg[n * 9 + 8] = v22;

#pragma unroll
    for (int j = 0; j < 15; ++j) {
        float x = 20.0f * sb2[j];
#pragma unroll
        for (int c = 0; c < 32; ++c) x += hs[c] * sW2[c * 15 + j];
        featO[n * 15 + j] = 1.0f / (1.0f + expf(-x));
    }
}

// ---------------------------------------------------------------------------
// Kernel 3: per-edge MLP via MFMA. One block (4 waves) per 2 points.
// ---------------------------------------------------------------------------
__global__ __launch_bounds__(256) void mlp_k(const int* __restrict__ nbr,
                                             const float* __restrict__ dirc,
                                             const float* __restrict__ featI,
                                             const float* __restrict__ Vg,
                                             const short* __restrict__ W3T,
                                             const float* __restrict__ b3,
                                             const short* __restrict__ W4T,
                                             const float* __restrict__ b4,
                                             float* __restrict__ pf)
{
    __shared__ __align__(16) short H1L[64 * 264];    // 33,792 B
    __shared__ __align__(16) short concatL[64 * 40]; //  5,120 B
    __shared__ int   nbr_s[40];
    __shared__ float Vr_s[18];

    const int t   = threadIdx.x;
    const int l   = t & 63;
    const int lg  = l >> 4;
    const int lc  = l & 15;
    const int n0w = (t >> 6) * 64;
    const int blk = blockIdx.x;

    if (t < 40) nbr_s[t] = nbr[blk * 40 + t];
    if (t >= 64 && t < 82) Vr_s[t - 64] = Vg[blk * 18 + (t - 64)];
    for (int i = t; i < 1280; i += 256) ((int*)concatL)[i] = 0;
    __syncthreads();

    for (int job = t; job < 720; job += 256) {
        int p  = job / 360;
        int rr = job - p * 360;
        int k  = rr / 18;
        int c  = rr - k * 18;
        int ptg = blk * 2 + p;
        float val;
        if (c < 3) {
            val = dirc[ptg * 60 + k * 3 + c];
        } else {
            int e = c - 3, g = e / 3, i = e - g * 3;
            const float* fp = featI + nbr_s[p * 20 + k] * 15 + g * 3;
            const float* Vr = Vr_s + p * 9;
            val = fp[0] * Vr[i * 3 + 0] + fp[1] * Vr[i * 3 + 1] + fp[2] * Vr[i * 3 + 2];
        }
        concatL[(32 * p + k) * 40 + c] = f2bf(val);
    }
    __syncthreads();

    {
        f32x4 accB[4][4];
#pragma unroll
        for (int mt = 0; mt < 4; ++mt)
#pragma unroll
            for (int nt = 0; nt < 4; ++nt)
#pragma unroll
                for (int r = 0; r < 4; ++r) accB[mt][nt][r] = 0.0f;

        bf16x8 aB[4], bB[4];
#pragma unroll
        for (int mt = 0; mt < 4; ++mt)
            aB[mt] = *(const bf16x8*)&concatL[(mt * 16 + lc) * 40 + lg * 8];
#pragma unroll
        for (int nt = 0; nt < 4; ++nt)
            bB[nt] = *(const bf16x8*)&W3T[(n0w + nt * 16 + lc) * 32 + lg * 8];
#pragma unroll
        for (int mt = 0; mt < 4; ++mt)
#pragma unroll
            for (int nt = 0; nt < 4; ++nt)
                accB[mt][nt] = __builtin_amdgcn_mfma_f32_16x16x32_bf16(aB[mt], bB[nt], accB[mt][nt], 0, 0, 0);

#pragma unroll
        for (int nt = 0; nt < 4; ++nt) {
            int col = n0w + nt * 16 + lc;
            float b3v = b3[col];
#pragma unroll
            for (int mt = 0; mt < 4; ++mt)
#pragma unroll
                for (int r = 0; r < 4; ++r) {
                    int row = mt * 16 + lg * 4 + r;
                    float v = fmaxf(accB[mt][nt][r] + b3v, 0.0f);
                    H1L[row * 264 + col] = f2bf(v);
                }
        }
    }
    __syncthreads();

    f32x4 acc[4][4];
#pragma unroll
    for (int mt = 0; mt < 4; ++mt)
#pragma unroll
        for (int nt = 0; nt < 4; ++nt)
#pragma unroll
            for (int r = 0; r < 4; ++r) acc[mt][nt][r] = 0.0f;

#pragma unroll
    for (int ch = 0; ch < 8; ++ch) {
        bf16x8 a[4], b[4];
#pragma unroll
        for (int mt = 0; mt < 4; ++mt)
            a[mt] = *(const bf16x8*)&H1L[(mt * 16 + lc) * 264 + ch * 32 + lg * 8];
#pragma unroll
        for (int nt = 0; nt < 4; ++nt)
            b[nt] = *(const bf16x8*)&W4T[(n0w + nt * 16 + lc) * 256 + ch * 32 + lg * 8];
#pragma unroll
        for (int mt = 0; mt < 4; ++mt)
#pragma unroll
            for (int nt = 0; nt < 4; ++nt)
                acc[mt][nt] = __builtin_amdgcn_mfma_f32_16x16x32_bf16(a[mt], b[nt], acc[mt][nt], 0, 0, 0);
    }

    const float mask = (lg == 0) ? 1.0f : 0.0f;
#pragma unroll
    for (int nt = 0; nt < 4; ++nt) {
        int col = n0w + nt * 16 + lc;
        float b4v = b4[col];
        float s0 = 0.0f, s1 = 0.0f;
#pragma unroll
        for (int r = 0; r < 4; ++r) {
            s0 += fmaxf(acc[0][nt][r] + b4v, 0.0f);
            s0 += fmaxf(acc[1][nt][r] + b4v, 0.0f) * mask;
            s1 += fmaxf(acc[2][nt][r] + b4v, 0.0f);
            s1 += fmaxf(acc[3][nt][r] + b4v, 0.0f) * mask;
        }
        s0 += __shfl_xor(s0, 16); s0 += __shfl_xor(s0, 32);
        s1 += __shfl_xor(s1, 16); s1 += __shfl_xor(s1, 32);
        if (l < 16) {
            pf[(blk * 2 + 0) * 256 + col] = s0;
            pf[(blk * 2 + 1) * 256 + col] = s1;
        }
    }
}

// ---------------------------------------------------------------------------
// Kernel 4a: partial sum over P: 128 blocks (16 batches x 8 slices of 128).
// ---------------------------------------------------------------------------
__global__ __launch_bounds__(256) void psum_k(const float* __restrict__ pf,
                                              float* __restrict__ partial)
{
    const int t   = threadIdx.x;
    const int blk = blockIdx.x;       // b = blk>>3, slice = blk&7
    const int b   = blk >> 3, sl = blk & 7;
    const float* basep = pf + ((size_t)b * NP + sl * 128) * 256 + t;
    float s = 0.0f;
#pragma unroll 8
    for (int p = 0; p < 128; ++p) s += basep[p * 256];
    partial[blk * 256 + t] = s;
}

// ---------------------------------------------------------------------------
// Kernel 4b: head proper (16 blocks).
// ---------------------------------------------------------------------------
__global__ __launch_bounds__(256) void head2_k(const float* __restrict__ partial,
                                               const float* __restrict__ Wn1,
                                               const float* __restrict__ bn1,
                                               const float* __restrict__ Wn2,
                                               const float* __restrict__ bn2,
                                               float* __restrict__ out)
{
    __shared__ float ysh[256], y1h[256], zsh[64];
    const int t = threadIdx.x, b = blockIdx.x;

    float s = 0.0f;
#pragma unroll
    for (int sl = 0; sl < 8; ++sl) s += partial[(b * 8 + sl) * 256 + t];
    ysh[t] = s * (1.0f / 1024.0f);
    __syncthreads();

    float acc = bn1[t];
    for (int c = 0; c < 256; ++c) acc += ysh[c] * Wn1[c * 256 + t];
    y1h[t] = (acc > 0.0f) ? acc : expm1f(acc);
    __syncthreads();

    if (t < NCLS) {
        float z = bn2[t];
        for (int c = 0; c < 256; ++c) z += y1h[c] * Wn2[c * NCLS + t];
        zsh[t] = z;
    }
    __syncthreads();

    if (t < 64) {
        float v = (t < NCLS) ? zsh[t] : -3.0e38f;
        float m = v;
#pragma unroll
        for (int off = 32; off >= 1; off >>= 1) m = fmaxf(m, __shfl_xor(m, off));
        float e = (t < NCLS) ? expf(zsh[t] - m) : 0.0f;
#pragma unroll
        for (int off = 32; off >= 1; off >>= 1) e += __shfl_xor(e, off);
        if (t < NCLS) out[b * NCLS + t] = zsh[t] - m - logf(e);
    }
}

// ---------------------------------------------------------------------------
extern "C" void kernel_launch(void* const* d_in, const int* in_sizes, int n_in,
                              void* d_out, int out_size, void* d_ws, size_t ws_size,
                              hipStream_t stream)
{
    const float* pos = (const float*)d_in[0];
    const float* W1  = (const float*)d_in[1];
    const float* b1  = (const float*)d_in[2];
    const float* W2  = (const float*)d_in[3];
    const float* b2  = (const float*)d_in[4];
    const float* W3  = (const float*)d_in[5];
    const float* b3  = (const float*)d_in[6];
    const float* W4  = (const float*)d_in[7];
    const float* b4  = (const float*)d_in[8];
    const float* Wn1 = (const float*)d_in[9];
    const float* bn1 = (const float*)d_in[10];
    const float* Wn2 = (const float*)d_in[11];
    const float* bn2 = (const float*)d_in[12];
    float* out = (float*)d_out;

    char* ws = (char*)d_ws;
    // workspace layout (bytes)
    int*   nbr     = (int*)(ws + 0);               //  1,310,720
    float* dirc    = (float*)(ws + 1310720);       //  3,932,160
    float* feat    = (float*)(ws + 5242880);       //    983,040
    float* Vg      = (float*)(ws + 6225920);       //    589,824
    float* pf      = (float*)(ws + 6815744);       // 16,777,216
    short* W4T     = (short*)(ws + 23592960);      //    131,072
    short* W3T     = (short*)(ws + 23724032);      //     16,384
    float* partial = (float*)(ws + 5242880);       // reuses feat region after mlp_k (131,072 B)

    prep_k <<<256,   256, 0, stream>>>(W3, W4, W3T, W4T);
    knn_k  <<<512,   256, 0, stream>>>(pos, nbr);
    geom_k <<<256,    64, 0, stream>>>(pos, nbr, W1, b1, W2, b2, dirc, feat, Vg);
    mlp_k  <<<NPT/2, 256, 0, stream>>>(nbr, dirc, feat, Vg, W3T, b3, W4T, b4, pf);
    psum_k <<<128,   256, 0, stream>>>(pf, partial);
    head2_k<<<NB,    256, 0, stream>>>(partial, Wn1, bn1, Wn2, bn2, out);
}